// Round 12
// baseline (1111.222 us; speedup 1.0000x reference)
//
#include <hip/hip_runtime.h>
#include <stdint.h>

typedef unsigned short u16;
typedef unsigned int u32;
typedef __attribute__((ext_vector_type(8))) __bf16 bf16x8;
typedef __attribute__((ext_vector_type(4))) float f32x4;

#define M_TOT 16384   // B*N tokens
#define DIMX  1024
#define NBLK  512     // grid size; 2 blocks/CU x 256 CU (64 KB LDS) => all co-resident

// RNE float->bf16 (finite inputs only)
__device__ __forceinline__ u16 f2b(float f) {
  u32 u = __builtin_bit_cast(u32, f);
  u32 r = (u + 0x7fffu + ((u >> 16) & 1u)) >> 16;
  return (u16)r;
}

__device__ __forceinline__ void gl2lds16(const void* g, void* l) {
  __builtin_amdgcn_global_load_lds((const __attribute__((address_space(1))) void*)g,
                                   (__attribute__((address_space(3))) void*)l,
                                   16, 0, 0);
}

// ---- grid barrier: release-fence -> arrive -> spin -> acquire-fence ----
// All 512 blocks are co-resident by construction (64 KB LDS => 2/CU).
__device__ __forceinline__ void gsync(u32* cnt, u32 thresh) {
  __threadfence();                 // release: per-wave writeback to coherent point
  __syncthreads();                 // all waves of this block have fenced
  if (threadIdx.x == 0) {
    atomicAdd(cnt, 1u);
    while (atomicAdd(cnt, 0u) < thresh) __builtin_amdgcn_s_sleep(2);
  }
  __syncthreads();
  __threadfence();                 // acquire: invalidate stale cached lines
}

// ======== GEMM core: 256x128, 8 waves, BK=32, dbuf, swizzled (R8, verified) ======
template<bool SWAP>
__device__ __forceinline__ f32x4 mf(bf16x8 a, bf16x8 b, f32x4 c) {
  return SWAP ? __builtin_amdgcn_mfma_f32_16x16x32_bf16(b, a, c, 0, 0, 0)
              : __builtin_amdgcn_mfma_f32_16x16x32_bf16(a, b, c, 0, 0, 0);
}

__device__ __forceinline__ void stage_ab(const u16* __restrict__ Ag,
                                         const u16* __restrict__ Bg,
                                         u16* dstA, u16* dstB, int t, int k0) {
#pragma unroll
  for (int r = 0; r < 2; r++) {
    int c = r * 512 + t;
    int row = c >> 2, s = c & 3;
    int g = s ^ ((row >> 1) & 3);                // inverse swizzle on source
    gl2lds16(Ag + (size_t)row * 1024 + k0 + g * 8,
             dstA + (r * 512 + (t >> 6) * 64) * 8);   // wave-uniform base
  }
  {
    int row = t >> 2, s = t & 3;
    int g = s ^ ((row >> 1) & 3);
    gl2lds16(Bg + (size_t)row * 1024 + k0 + g * 8,
             dstB + ((t >> 6) * 64) * 8);
  }
}

template<bool SWAP>
__device__ __forceinline__ void gemm_core(const u16* __restrict__ Ag,
                                          const u16* __restrict__ Bg,
                                          u16* lds, int t, f32x4 (&acc)[4][4]) {
  const int lane = t & 63;
  const int r16 = lane & 15, q = lane >> 4;
  const int wr = (t >> 6) >> 1, wc = (t >> 6) & 1;
  const int arow = wr * 64 + r16;
  const int brow = wc * 64 + r16;

  stage_ab(Ag, Bg, lds, lds + 8192, t, 0);
  asm volatile("s_waitcnt vmcnt(0)" ::: "memory");
  __builtin_amdgcn_s_barrier();

  bf16x8 af[4], bf[4];
#pragma unroll 1
  for (int tt = 0; tt < 32; tt++) {
    const int cur = (tt & 1) ? 12288 : 0;
    const int nxt = cur ^ 12288;
    const int k1 = ((tt + 1) & 31) << 5;  // next K (wraps: harmless re-stage)
    stage_ab(Ag, Bg, lds + nxt, lds + nxt + 8192, t, k1);
    const u16* A = lds + cur;
    const u16* B = lds + cur + 8192;
#pragma unroll
    for (int i = 0; i < 4; i++) {
      int ar = i * 16 + arow;
      int br = i * 16 + brow;
      af[i] = *(const bf16x8*)(A + ar * 32 + (q ^ ((ar >> 1) & 3)) * 8);
      bf[i] = *(const bf16x8*)(B + br * 32 + (q ^ ((br >> 1) & 3)) * 8);
    }
    __builtin_amdgcn_s_setprio(1);
#pragma unroll
    for (int i = 0; i < 4; i++)
#pragma unroll
      for (int j = 0; j < 4; j++)
        acc[i][j] = mf<SWAP>(af[i], bf[j], acc[i][j]);
    __builtin_amdgcn_s_setprio(0);
    asm volatile("s_waitcnt vmcnt(0)" ::: "memory");
    __builtin_amdgcn_s_barrier();
  }
}

// =================== the persistent mega-kernel ===================
__global__ __launch_bounds__(512, 4) void k_mega(
    const float* __restrict__ x, const float* __restrict__ gamma,
    const float* __restrict__ wqkv, const float* __restrict__ wout,
    const float* __restrict__ temp,
    u16* __restrict__ xn, u16* __restrict__ wqT, u16* __restrict__ woT,
    u16* __restrict__ qkT, u16* __restrict__ vmat,
    float* __restrict__ sumsq, u16* __restrict__ MT,
    float* __restrict__ Spart, float* __restrict__ out, u32* cnt) {
  __shared__ __align__(16) char smem[65536];
  const int t = threadIdx.x;
  const int blk = blockIdx.x;
  const int lane = t & 63;
  const int r16 = lane & 15, q = lane >> 4;

  // ---------------- P0: RMSNorm (16384 vblocks) + weight prep (4096 vblocks) ------
  {
    float* tile = (float*)smem;                      // [2][32][33] = 8448 B
    float* wss  = (float*)(smem + 8448);             // [2][4]
    int vb = t >> 8;          // virtual block 0/1 (wave-uniform: waves 0-3 / 4-7)
    int tl = t & 255;
#pragma unroll 1
    for (int i = 0; i < 20; i++) {
      int v = blk * 2 + vb + i * 1024;               // 0..20479 exactly
      if (v < 16384) {
        const float4* xr = (const float4*)(x + (size_t)v * DIMX);
        float4 vv = xr[tl];
        float ss = vv.x * vv.x + vv.y * vv.y + vv.z * vv.z + vv.w * vv.w;
#pragma unroll
        for (int o = 32; o > 0; o >>= 1) ss += __shfl_xor(ss, o, 64);
        if ((tl & 63) == 0) wss[vb * 4 + (tl >> 6)] = ss;
        __syncthreads();
        float tot = wss[vb * 4 + 0] + wss[vb * 4 + 1] + wss[vb * 4 + 2] + wss[vb * 4 + 3];
        float scale = 32.0f / fmaxf(sqrtf(tot), 1e-12f);
        float4 g = ((const float4*)gamma)[tl];
        ushort4 o4;
        o4.x = f2b(vv.x * scale * g.x);
        o4.y = f2b(vv.y * scale * g.y);
        o4.z = f2b(vv.z * scale * g.z);
        o4.w = f2b(vv.w * scale * g.w);
        ((ushort4*)xn)[(size_t)v * 256 + tl] = o4;
      } else {
        int bb = v - 16384;              // 0..4095
        int bx = bb & 127, by = bb >> 7; // (128, 32)
        int r0 = by * 32;
        int tx = tl & 31, ty = tl >> 5;
        const float* in; u16* outp; int Cc, c0;
        if (bx < 96) { in = wqkv; outp = wqT; Cc = 3072; c0 = bx * 32; }
        else         { in = wout; outp = woT; Cc = 1024; c0 = (bx - 96) * 32; }
        float* tl2 = tile + vb * 32 * 33;
#pragma unroll
        for (int i2 = 0; i2 < 4; i2++)
          tl2[(ty + i2 * 8) * 33 + tx] = in[(size_t)(r0 + ty + i2 * 8) * Cc + c0 + tx];
        __syncthreads();
#pragma unroll
        for (int i2 = 0; i2 < 4; i2++)
          outp[(size_t)(c0 + ty + i2 * 8) * 1024 + r0 + tx] = f2b(tl2[tx * 33 + ty + i2 * 8]);
      }
      __syncthreads();   // WAR across iterations (both paths: uniform 2 syncs/iter)
    }
  }
  gsync(cnt, NBLK);

  // ---------------- P1: gemm1 merged q/k/v — 1536 tiles, 3 per block --------------
  {
    u16* lds = (u16*)smem;   // 48 KB
#pragma unroll 1
    for (int i = 0; i < 3; i++) {
      int l = blk + i * NBLK;
      int xcd = l & 7, c = l >> 3;
      int mt = xcd * 8 + (c & 7);
      int nt = c >> 3;
      int m0 = mt * 256, n0 = nt * 128;
      int wr = (t >> 6) >> 1, wc = (t >> 6) & 1;
      f32x4 acc[4][4] = {};
      if (n0 < 2048) {
        gemm_core<false>(xn + (size_t)m0 * 1024, wqT + (size_t)n0 * 1024, lds, t, acc);
        int b = m0 >> 12;
#pragma unroll
        for (int j = 0; j < 4; j++) {
          int cc = n0 + wc * 64 + j * 16 + r16;
          float colss = 0.f;
#pragma unroll
          for (int i2 = 0; i2 < 4; i2++) {
            f32x4 a = acc[i2][j];
            colss += a.x * a.x + a.y * a.y + a.z * a.z + a.w * a.w;
            int m = m0 + wr * 64 + i2 * 16 + q * 4;
            ushort4 o4;
            o4.x = f2b(a.x); o4.y = f2b(a.y); o4.z = f2b(a.z); o4.w = f2b(a.w);
            *(ushort4*)(qkT + (size_t)cc * M_TOT + m) = o4;
          }
          colss += __shfl_xor(colss, 16, 64);
          colss += __shfl_xor(colss, 32, 64);
          if (lane < 16) atomicAdd(&sumsq[b * 2048 + cc], colss);
        }
      } else {
        gemm_core<true>(xn + (size_t)m0 * 1024, wqT + (size_t)n0 * 1024, lds, t, acc);
        int vc0 = n0 - 2048;
#pragma unroll
        for (int i2 = 0; i2 < 4; i2++) {
          int m = m0 + wr * 64 + i2 * 16 + r16;
#pragma unroll
          for (int j = 0; j < 4; j++) {
            int cc = vc0 + wc * 64 + j * 16 + q * 4;
            f32x4 a = acc[i2][j];
            ushort4 o4;
            o4.x = f2b(a.x); o4.y = f2b(a.y); o4.z = f2b(a.z); o4.w = f2b(a.w);
            *(ushort4*)(vmat + (size_t)m * 1024 + cc) = o4;
          }
        }
      }
    }
  }
  gsync(cnt, 2 * NBLK);

  // ---------------- P2: S partials — 512 blocks = 64 bh x 8 n-splits --------------
  // 8 waves: wl = w&3 owns d-strip, wg = w>>2 owns contraction parity.
  // 16 partials: sp = split*2 + wg.  Spart[16][64][64][64] f32 (16 MB, aliases xn).
  {
    u16* Ql = (u16*)smem;            // 32 KB
    u16* Kl = (u16*)smem + 16384;    // 32 KB
    int bh = blk & 63, split = blk >> 6;
    int b = bh >> 4, h = bh & 15;
    int w = t >> 6, wl = w & 3, wg = w >> 2;
    const u16* qbase = qkT + (size_t)(h * 64) * M_TOT + b * 4096 + split * 512;
    const u16* kbase = qkT + (size_t)(1024 + h * 64) * M_TOT + b * 4096 + split * 512;
    int drow = wl * 16 + r16;
    f32x4 acc[4] = {};
#pragma unroll 1
    for (int it = 0; it < 2; it++) {
      int ncol = it * 256;
#pragma unroll
      for (int r = 0; r < 4; r++) {
        int ch = r * 512 + t;
        int row = ch >> 5;
        int sl = (ch & 31) ^ (row & 31);   // inverse swizzle on source
        gl2lds16(qbase + (size_t)row * M_TOT + ncol + sl * 8,
                 Ql + (r * 512 + w * 64) * 8);
        gl2lds16(kbase + (size_t)row * M_TOT + ncol + sl * 8,
                 Kl + (r * 512 + w * 64) * 8);
      }
      asm volatile("s_waitcnt vmcnt(0)" ::: "memory");
      __syncthreads();
#pragma unroll
      for (int h2 = 0; h2 < 4; h2++) {
        int it2 = h2 * 2 + wg;
        bf16x8 aq = *(const bf16x8*)(Ql + drow * 256 + (((it2 * 4 + q) ^ (drow & 31)) * 8));
#pragma unroll
        for (int j = 0; j < 4; j++) {
          int erow = j * 16 + r16;
          bf16x8 bk = *(const bf16x8*)(Kl + erow * 256 + (((it2 * 4 + q) ^ (erow & 31)) * 8));
          acc[j] = __builtin_amdgcn_mfma_f32_16x16x32_bf16(bk, aq, acc[j], 0, 0, 0);
        }
      }
      __syncthreads();
    }
    int sp = split * 2 + wg;               // 0..15
    float* Sp = Spart + ((size_t)sp * 64 + bh) * 4096;
#pragma unroll
    for (int j = 0; j < 4; j++)
      *(f32x4*)(Sp + drow * 64 + j * 16 + q * 4) = acc[j];
  }
  gsync(cnt, 3 * NBLK);

  // ---------------- P3: softmax (PT in LDS) + k_m — blocks 0..63 ------------------
  if (blk < 64) {
    u16* PT_lds = (u16*)smem;                 // 8 KB: PT[e][d]
    float* rnk  = (float*)(smem + 8192);      // 64
    float* redm = (float*)(smem + 8448);      // [8][64]
    float* reds = (float*)(smem + 10496);     // [8][64]
    int bh = blk;
    int b = bh >> 4, h = bh & 15;
    int d = t & 63, w = t >> 6;               // w in 0..7
    int e0 = w * 8;
    if (t < 64) rnk[t] = 1.0f / fmaxf(sqrtf(sumsq[b * 2048 + 1024 + h * 64 + t]), 1e-12f);
    __syncthreads();
    float nq = sqrtf(sumsq[b * 2048 + h * 64 + d]);
    float qs = 8.0f * __expf(temp[h]) / fmaxf(nq, 1e-12f);
    float vals[8];
#pragma unroll
    for (int e = 0; e < 8; e += 4) {
      f32x4 v = {};
#pragma unroll
      for (int s = 0; s < 16; s++)
        v += *(const f32x4*)(Spart + ((size_t)s * 64 + bh) * 4096 + d * 64 + e0 + e);
      vals[e + 0] = v.x; vals[e + 1] = v.y; vals[e + 2] = v.z; vals[e + 3] = v.w;
    }
    float mx = -3.0e38f;
#pragma unroll
    for (int e = 0; e < 8; e++) {
      float v = vals[e] * qs * rnk[e0 + e];
      vals[e] = v;
      mx = fmaxf(mx, v);
    }
    redm[w * 64 + d] = mx;
    __syncthreads();
    float M = redm[d];
#pragma unroll
    for (int k = 1; k < 8; k++) M = fmaxf(M, redm[k * 64 + d]);
    float ssum = 0.f;
#pragma unroll
    for (int e = 0; e < 8; e++) {
      float v = __expf(vals[e] - M);
      vals[e] = v;
      ssum += v;
    }
    reds[w * 64 + d] = ssum;
    __syncthreads();
    float tot = reds[d];
#pragma unroll
    for (int k = 1; k < 8; k++) tot += reds[k * 64 + d];
    float inv = 1.0f / tot;
#pragma unroll
    for (int e = 0; e < 8; e++)
      PT_lds[(e0 + e) * 64 + d] = f2b(vals[e] * inv);
    __syncthreads();
    // ---- k_m: MT_b[o][h*64+e] = sum_d woT[o][h*64+d] * PT[e][d]  (PT from LDS) ----
    int tl = t & 255, vb = t >> 8;
    int lane2 = tl & 63, w4 = tl >> 6;
    int r2 = lane2 & 15, q2 = lane2 >> 4;
    u16* dst = MT + (size_t)b * 1024 * 1024;
#pragma unroll 1
    for (int ot = vb; ot < 8; ot += 2) {
      int o0 = ot * 128;
      f32x4 acc2[2][4] = {};
#pragma unroll
      for (int ks = 0; ks < 2; ks++) {
        int kk = ks * 32 + q2 * 8;
        bf16x8 af[2], bfr[4];
#pragma unroll
        for (int i = 0; i < 2; i++)
          af[i] = *(const bf16x8*)(woT + (size_t)(o0 + w4 * 32 + i * 16 + r2) * 1024 + h * 64 + kk);
#pragma unroll
        for (int j = 0; j < 4; j++)
          bfr[j] = *(const bf16x8*)(PT_lds + (size_t)(j * 16 + r2) * 64 + kk);
#pragma unroll
        for (int i = 0; i < 2; i++)
#pragma unroll
          for (int j = 0; j < 4; j++)
            acc2[i][j] = __builtin_amdgcn_mfma_f32_16x16x32_bf16(af[i], bfr[j], acc2[i][j], 0, 0, 0);
      }
#pragma unroll
      for (int i = 0; i < 2; i++) {
        int o = o0 + w4 * 32 + i * 16 + q2 * 4;
#pragma unroll
        for (int j = 0; j < 4; j++) {
          int e = h * 64 + j * 16 + r2;
          f32x4 a = acc2[i][j];
          dst[(size_t)(o + 0) * 1024 + e] = f2b(a.x);
          dst[(size_t)(o + 1) * 1024 + e] = f2b(a.y);
          dst[(size_t)(o + 2) * 1024 + e] = f2b(a.z);
          dst[(size_t)(o + 3) * 1024 + e] = f2b(a.w);
        }
      }
    }
  }
  gsync(cnt, 4 * NBLK);

  // ---------------- P4: gemm2 out = vmat @ MT_b^T (fp32), 512 tiles ---------------
  {
    u16* lds = (u16*)smem;   // 48 KB
    int l = blk;
    int xcd = l & 7, c = l >> 3;        // c in [0,64)
    int mt = xcd * 8 + (c & 7);         // 0..63
    int nt = c >> 3;                    // 0..7
    int m0 = mt * 256, n0 = nt * 128;
    int b = m0 >> 12;
    int wr = (t >> 6) >> 1, wc = (t >> 6) & 1;
    f32x4 acc[4][4] = {};
    gemm_core<true>(vmat + (size_t)m0 * 1024,
                    MT + (size_t)b * 1048576 + (size_t)n0 * 1024, lds, t, acc);
#pragma unroll
    for (int i = 0; i < 4; i++) {
      int m = m0 + wr * 64 + i * 16 + r16;
#pragma unroll
      for (int j = 0; j < 4; j++) {
        int cc = n0 + wc * 64 + j * 16 + q * 4;
        *(f32x4*)(out + (size_t)m * 1024 + cc) = acc[i][j];
      }
    }
  }
}

extern "C" void kernel_launch(void* const* d_in, const int* in_sizes, int n_in,
                              void* d_out, int out_size, void* d_ws, size_t ws_size,
                              hipStream_t stream) {
  const float* x     = (const float*)d_in[0];
  const float* gamma = (const float*)d_in[1];
  const float* wqkv  = (const float*)d_in[2];
  const float* temp  = (const float*)d_in[3];
  const float* wout  = (const float*)d_in[4];
  float* out = (float*)d_out;

  char* ws = (char*)d_ws;
  size_t off = 0;
  u16* xn = (u16*)(ws + off);    off += (size_t)M_TOT * 1024 * 2;   // 32M (dead after P1)
  u16* wqT = (u16*)(ws + off);   off += (size_t)3072 * 1024 * 2;
  u16* woT = (u16*)(ws + off);   off += (size_t)1024 * 1024 * 2;
  u16* qkT = (u16*)(ws + off);   off += (size_t)2048 * M_TOT * 2;
  u16* vmat = (u16*)(ws + off);  off += (size_t)M_TOT * 1024 * 2;
  float* sumsq = (float*)(ws + off); off += (size_t)4 * 2048 * 4;
  u32* cnt = (u32*)(ws + off);   off += 64;
  u16* MT = (u16*)(ws + off);    off += (size_t)4 * 1024 * 1024 * 2;

  // Spart[16][64][64][64] fp32 (16 MB) aliases xn (32 MB), dead after P1.
  float* Spart = (float*)xn;

  // zero sumsq (atomic-accumulated) + barrier counter, every replay
  hipMemsetAsync((void*)sumsq, 0, (size_t)4 * 2048 * 4 + 64, stream);

  k_mega<<<NBLK, 512, 0, stream>>>(x, gamma, wqkv, wout, temp,
                                   xn, wqT, woT, qkT, vmat,
                                   sumsq, MT, Spart, out, cnt);
}